// Round 21
// baseline (277.030 us; speedup 1.0000x reference)
//
#include <hip/hip_runtime.h>

typedef unsigned int u32;
typedef unsigned short u16;
typedef __attribute__((ext_vector_type(8))) short s8v;
typedef __attribute__((ext_vector_type(8))) __bf16 b8v;
typedef __attribute__((ext_vector_type(4))) float f4v;
typedef __attribute__((ext_vector_type(16))) float f32x16;
typedef __attribute__((ext_vector_type(4))) u32 u32x4;
typedef __attribute__((ext_vector_type(2))) u32 u32x2;

#define DEV static __device__ __forceinline__

DEV u32 cvtpk(float a, float b){ u32 r; asm("v_cvt_pk_bf16_f32 %0, %1, %2" : "=v"(r) : "v"(a), "v"(b)); return r; }
DEV u16 f2bf(float x){ return (u16)(cvtpk(x, x) & 0xffffu); }
DEV float bf2f(u16 u){ return __builtin_bit_cast(float, ((u32)u) << 16); }

DEV f4v mfma16(s8v a, s8v b, f4v c){
  return __builtin_amdgcn_mfma_f32_16x16x32_bf16(__builtin_bit_cast(b8v, a), __builtin_bit_cast(b8v, b), c, 0, 0, 0);
}
DEV f32x16 mfma32(s8v a, s8v b, f32x16 c){
  return __builtin_amdgcn_mfma_f32_32x32x16_bf16(__builtin_bit_cast(b8v, a), __builtin_bit_cast(b8v, b), c, 0, 0, 0);
}

DEV void gl_lds16(const void* g, void* l){
  __builtin_amdgcn_global_load_lds((const __attribute__((address_space(1))) u32*)g,
                                   (__attribute__((address_space(3))) u32*)l, 16, 0, 0);
}

// ---------------- prep: X fp32 -> bf16 (16 elems/thread) ----------------
__global__ __launch_bounds__(256) void k_prepx(const float* __restrict__ x, u16* __restrict__ xb, int n){
  int i = (blockIdx.x * 256 + threadIdx.x) * 16;
  if (i >= n) return;
  float4 a = *(const float4*)(x + i);
  float4 b = *(const float4*)(x + i + 4);
  float4 c = *(const float4*)(x + i + 8);
  float4 d = *(const float4*)(x + i + 12);
  u32x4 o0, o1;
  o0.x = cvtpk(a.x, a.y); o0.y = cvtpk(a.z, a.w);
  o0.z = cvtpk(b.x, b.y); o0.w = cvtpk(b.z, b.w);
  o1.x = cvtpk(c.x, c.y); o1.y = cvtpk(c.z, c.w);
  o1.z = cvtpk(d.x, d.y); o1.w = cvtpk(d.z, d.w);
  *(u32x4*)(xb + i) = o0;
  *(u32x4*)(xb + i + 8) = o1;
}

// ---------------- prep: batched transpose of Wq/Wk/Wv/Wo fp32 [1152][N] -> bf16 [N][1152] ----------------
__global__ __launch_bounds__(256) void k_transpose4(const float* __restrict__ Wq, const float* __restrict__ Wk,
                                                    const float* __restrict__ Wv, const float* __restrict__ Wo,
                                                    u16* __restrict__ WtQKV, u16* __restrict__ Wot){
  __shared__ float t[32][33];
  int cse = blockIdx.y;
  const float* src; u16* dst; int N;
  if (cse == 0){ src = Wq; dst = WtQKV;               N = 1152; }
  else if (cse == 1){ src = Wk; dst = WtQKV + 1152 * 1152; N = 576; }
  else if (cse == 2){ src = Wv; dst = WtQKV + 1728 * 1152; N = 576; }
  else { src = Wo; dst = Wot;                         N = 1152; }
  int nt = N >> 5;
  if ((int)blockIdx.x >= 36 * nt) return;
  int k0 = (blockIdx.x / nt) << 5, n0 = (blockIdx.x % nt) << 5;
  int col = threadIdx.x & 31, rw = threadIdx.x >> 5;
  #pragma unroll
  for (int i = 0; i < 4; i++){ int r = rw + i * 8; t[r][col] = src[(k0 + r) * N + n0 + col]; }
  __syncthreads();
  #pragma unroll
  for (int i = 0; i < 4; i++){ int r = rw + i * 8; dst[(n0 + r) * 1152 + k0 + col] = f2bf(t[col][r]); }
}

// ---------------- GEMM: C[M,N] = A[M,K] * Bt[N,K]^T, bf16 in, bf16 or f32 out ----------------
template<int OUTF32>
__global__ __launch_bounds__(256) void k_gemm(const u16* __restrict__ A, const u16* __restrict__ Bt,
                                              void* __restrict__ Cv, int M, int N, int K){
  __shared__ u16 sA[128 * 64];
  __shared__ u16 sB[128 * 64];
  int tid = threadIdx.x, w = tid >> 6, lane = tid & 63, g = lane >> 4, c = lane & 15;
  int n0 = blockIdx.x << 7, m0 = blockIdx.y << 7;
  int wr = w >> 1, wc = w & 1;
  f4v acc[4][4] = {};
  int srow = lane >> 3;
  int sslot = (lane & 7) ^ srow;
  const u16* Abase = A + (m0 + srow) * K + sslot * 8;
  const u16* Bbase = Bt + (n0 + srow) * K + sslot * 8;
  #pragma unroll 1
  for (int kt = 0; kt < K; kt += 64){
    #pragma unroll
    for (int ii = 0; ii < 4; ii++){
      int i = w * 4 + ii;
      gl_lds16(Abase + i * 8 * K + kt, sA + i * 512);
      gl_lds16(Bbase + i * 8 * K + kt, sB + i * 512);
    }
    __syncthreads();
    #pragma unroll
    for (int kk = 0; kk < 2; kk++){
      s8v af[4], bfr[4];
      #pragma unroll
      for (int mi = 0; mi < 4; mi++){
        int r = (wr << 6) + (mi << 4) + c;
        int slot = ((kk << 2) + g) ^ (r & 7);
        af[mi] = *(const s8v*)(sA + r * 64 + slot * 8);
      }
      #pragma unroll
      for (int ni = 0; ni < 4; ni++){
        int r = (wc << 6) + (ni << 4) + c;
        int slot = ((kk << 2) + g) ^ (r & 7);
        bfr[ni] = *(const s8v*)(sB + r * 64 + slot * 8);
      }
      #pragma unroll
      for (int mi = 0; mi < 4; mi++)
        #pragma unroll
        for (int ni = 0; ni < 4; ni++)
          acc[mi][ni] = mfma16(af[mi], bfr[ni], acc[mi][ni]);
    }
    __syncthreads();
  }
  #pragma unroll
  for (int mi = 0; mi < 4; mi++){
    #pragma unroll
    for (int ni = 0; ni < 4; ni++){
      #pragma unroll
      for (int r = 0; r < 4; r++){
        int m = m0 + (wr << 6) + (mi << 4) + (g << 2) + r;
        int n = n0 + (wc << 6) + (ni << 4) + c;
        if (OUTF32) ((float*)Cv)[m * N + n] = acc[mi][ni][r];
        else        ((u16*)Cv)[m * N + n] = f2bf(acc[mi][ni][r]);
      }
    }
  }
}

// ---------------- RMSNorm + RoPE; vectorized input staging via LDS ----------------
// Q -> stride 96 (zeros 72..95, xlog2e), K -> stride 128 (zeros 72..127)
__global__ __launch_bounds__(192) void k_normrope(const u16* __restrict__ Y, const float* __restrict__ cosp,
      const float* __restrict__ sinp, const float* __restrict__ qnw, const float* __restrict__ knw,
      u16* __restrict__ Qp, u16* __restrict__ Kp){
  __shared__ float ly[1728];
  int token = blockIdx.x;
  int t = threadIdx.x, head = t >> 3, j = t & 7;
  int base = head * 72 + j * 9;
  if (t < 144){
    const u32* yru = (const u32*)(Y + (size_t)token * 2304) + t * 6;
    u32x2 c0 = *(const u32x2*)(yru);
    u32x2 c1 = *(const u32x2*)(yru + 2);
    u32x2 c2 = *(const u32x2*)(yru + 4);
    float* lp = &ly[t * 12];
    f4v f0, f1, f2;
    f0[0] = bf2f((u16)(c0.x & 0xffff)); f0[1] = bf2f((u16)(c0.x >> 16));
    f0[2] = bf2f((u16)(c0.y & 0xffff)); f0[3] = bf2f((u16)(c0.y >> 16));
    f1[0] = bf2f((u16)(c1.x & 0xffff)); f1[1] = bf2f((u16)(c1.x >> 16));
    f1[2] = bf2f((u16)(c1.y & 0xffff)); f1[3] = bf2f((u16)(c1.y >> 16));
    f2[0] = bf2f((u16)(c2.x & 0xffff)); f2[1] = bf2f((u16)(c2.x >> 16));
    f2[2] = bf2f((u16)(c2.y & 0xffff)); f2[3] = bf2f((u16)(c2.y >> 16));
    *(f4v*)(lp) = f0; *(f4v*)(lp + 4) = f1; *(f4v*)(lp + 8) = f2;
  }
  __syncthreads();
  float x[9]; float ss = 0.f;
  #pragma unroll
  for (int i = 0; i < 9; i++){ x[i] = ly[base + i]; ss += x[i] * x[i]; }
  ss += __shfl_xor(ss, 1); ss += __shfl_xor(ss, 2); ss += __shfl_xor(ss, 4);
  float inv = rsqrtf(ss * (1.f / 72.f) + 1e-6f);
  const float* wn = (head < 16) ? qnw : knw;
  #pragma unroll
  for (int i = 0; i < 9; i++){ int d = j * 9 + i; ly[base + i] = x[i] * inv * (1.f + wn[d]); }
  __syncthreads();
  const float* cs = cosp + token * 72;
  const float* sn = sinp + token * 72;
  float scale = (head < 16) ? 1.4426950408889634f : 1.0f;
  float o[9];
  #pragma unroll
  for (int i = 0; i < 9; i++){
    int d = j * 9 + i;
    int dm = (d >= 36) ? d - 36 : d;
    float rot = (dm < 18) ? -ly[head * 72 + d + 18] : ly[head * 72 + d - 18];
    o[i] = (ly[base + i] * cs[d] + rot * sn[d]) * scale;
  }
  int b = token >> 11, s = token & 2047;
  if (head < 16){
    u16* dst = Qp + (size_t)(((b << 4) + head) * 2048 + s) * 96;
    #pragma unroll
    for (int i = 0; i < 9; i++) dst[j * 9 + i] = f2bf(o[i]);
    #pragma unroll
    for (int p2 = 0; p2 < 3; p2++) dst[72 + j * 3 + p2] = 0;
  } else {
    u16* dst = Kp + (size_t)(((b << 3) + (head - 16)) * 2048 + s) * 128;
    #pragma unroll
    for (int i = 0; i < 9; i++) dst[j * 9 + i] = f2bf(o[i]);
    #pragma unroll
    for (int p2 = 0; p2 < 7; p2++) dst[72 + j * 7 + p2] = 0;
  }
}

// ---------------- V: RMSNorm (no scale) + transpose -> Vt [4][8][72][2048] ----------------
// Input staged via global_load_lds: chunk n (0..287) maps dst byte = 16n (lane-linear),
// src = row n/9, 16B-piece n%9 (both 16B-aligned).
__global__ __launch_bounds__(256) void k_vtrans(const u16* __restrict__ Y, u16* __restrict__ Vt){
  __shared__ u16 sraw[32 * 72];     // 4608 B raw bf16 rows
  __shared__ float lv[72][33];
  int st = blockIdx.x, bk = blockIdx.y;
  int b = bk >> 3, kvh = bk & 7;
  int t = threadIdx.x, tl = t >> 3, j = t & 7;
  int token0 = (b << 11) + (st << 5);
  const char* ybase = (const char*)(Y + (size_t)token0 * 2304 + 1728 + kvh * 72);
  {
    int n0 = t, r0 = n0 / 9, c0 = n0 % 9;
    gl_lds16(ybase + (size_t)r0 * 4608 + c0 * 16, (char*)sraw + n0 * 16);
    if (t < 32){
      int n1 = 256 + t, r1 = n1 / 9, c1 = n1 % 9;
      gl_lds16(ybase + (size_t)r1 * 4608 + c1 * 16, (char*)sraw + n1 * 16);
    }
  }
  __syncthreads();
  float x[9]; float ss = 0.f;
  #pragma unroll
  for (int i = 0; i < 9; i++){ x[i] = bf2f(sraw[tl * 72 + j * 9 + i]); ss += x[i] * x[i]; }
  ss += __shfl_xor(ss, 1); ss += __shfl_xor(ss, 2); ss += __shfl_xor(ss, 4);
  float inv = rsqrtf(ss * (1.f / 72.f) + 1e-6f);
  #pragma unroll
  for (int i = 0; i < 9; i++) lv[j * 9 + i][tl] = x[i] * inv;
  __syncthreads();
  u16* vb = Vt + (size_t)bk * 72 * 2048 + (st << 5);
  for (int e = t; e < 72 * 32; e += 256){
    int r = e >> 5, cl = e & 31;
    vb[r * 2048 + cl] = f2bf(lv[r][cl]);
  }
}

// ---------------- Flash attention: 32x32x16, KT=64, head-pairing, 2 blocks/CU, per-subtile pipeline ----------------
// grid (32 bk, 16 qt) = 512 blocks, all resident (2/CU, 4 waves/SIMD).
// 8 waves: w<4 -> head 2kv, w>=4 -> head 2kv+1; 32 q-rows/wave; 2 key-subtiles of 32 per 64-key tile.
// Defer-rescale THR=16 (P <= 2^16; ls <= 1.3e8 -- ample fp32/bf16 margin; R13 proved THR=inf safe).
__global__ __launch_bounds__(512, 4) void k_attn(const u16* __restrict__ Qp, const u16* __restrict__ Kp,
                                                 const u16* __restrict__ Vt, u16* __restrict__ O){
  __shared__ u16 sK[2][64 * 128];   // [buf][key][16 slots of 8]; phys slot = s ^ (key&15)   32KB
  __shared__ u16 sV[2][48 * 128];   // [buf][R=d>>1][slot16 of 8 u16]; slot16 = ((sp<<1)|(d&1)) ^ (R&15)  24KB
  int tid = threadIdx.x, w = tid >> 6, lane = tid & 63, hi = lane >> 5, l31 = lane & 31;
  int bk = blockIdx.x, qt = blockIdx.y;     // 16 qt-blocks of bk land on XCD bk&7
  int b = bk >> 3, kv = bk & 7;
  int h = (kv << 1) + (w >> 2);
  int q = (qt << 7) + ((w & 3) << 5) + l31;
  const u16* qb = Qp + (size_t)((((b << 4) + h) << 11) + q) * 96;
  s8v qf[5];
  #pragma unroll
  for (int ds = 0; ds < 5; ds++) qf[ds] = *(const s8v*)(qb + ds * 16 + hi * 8);
  f32x16 ao[3] = {};
  float mv = -3.0e38f, lsp = 0.f;
  const char* kb = (const char*)Kp + (size_t)bk * 2048 * 256;
  const char* vb = (const char*)Vt + (size_t)bk * 72 * 4096;
  int ko[2], kd[2];
  #pragma unroll
  for (int i = 0; i < 2; i++){
    int n = i * 512 + tid;
    int kr = n >> 4, sp = n & 15;
    ko[i] = kr * 256 + ((sp ^ (kr & 15)) << 4);
    kd[i] = n << 4;
  }
  int vo[2], vd[2];
  #pragma unroll
  for (int i = 0; i < 2; i++){
    int n = (i == 0) ? tid : (512 + lane);
    int R = n >> 4, sl = n & 15, v = sl ^ (R & 15);
    vo[i] = (R * 2 + (v & 1)) * 4096 + ((v >> 1) << 4);
    vd[i] = n << 4;
  }
  int rhalf = l31 >> 1, bbit = l31 & 1;   // PV read geometry: R = dt*16 + rhalf, d = dt*32 + l31

#define STAGE(buf, t1) { \
    const char* kt_ = kb + (size_t)(t1) * 16384; \
    gl_lds16(kt_ + ko[0], (char*)sK[buf] + kd[0]); \
    gl_lds16(kt_ + ko[1], (char*)sK[buf] + kd[1]); \
    const char* vt_ = vb + (size_t)(t1) * 128; \
    gl_lds16(vt_ + vo[0], (char*)sV[buf] + vd[0]); \
    if (w == 0) gl_lds16(vt_ + vo[1], (char*)sV[buf] + vd[1]); }

#define MK_PF(S, mlo, PF) { \
      u32 a0 = cvtpk(S[mlo + 0], S[mlo + 1]); \
      u32 a1 = cvtpk(S[mlo + 2], S[mlo + 3]); \
      u32 b0 = cvtpk(S[mlo + 4], S[mlo + 5]); \
      u32 b1 = cvtpk(S[mlo + 6], S[mlo + 7]); \
      asm("v_permlane32_swap_b32 %0, %1" : "+v"(a0), "+v"(b0)); \
      asm("v_permlane32_swap_b32 %0, %1" : "+v"(a1), "+v"(b1)); \
      u32x4 w4 = {a0, a1, b0, b1}; \
      PF = __builtin_bit_cast(s8v, w4); }

  STAGE(0, 0)
  __syncthreads();

  #pragma unroll 1
  for (int t = 0; t < 32; t++){
    int cur = t & 1, nxt = cur ^ 1;
    if (t < 31){ STAGE(nxt, t + 1) }
    const u16* sKc = sK[cur];
    const u16* sVc = sV[cur];
    #pragma unroll
    for (int j = 0; j < 2; j++){
      // ---- QK^T subtile j: C[key][q], keys j*32..j*32+31 ----
      f32x16 sc = {};
      int r = j * 32 + l31;
      __builtin_amdgcn_s_setprio(1);
      #pragma unroll
      for (int ds = 0; ds < 5; ds++){
        int s = ds * 2 + hi;
        s8v kf = *(const s8v*)(sKc + r * 128 + ((s ^ (r & 15)) << 3));
        sc = mfma32(kf, qf[ds], sc);
      }
      __builtin_amdgcn_s_setprio(0);
      // ---- online softmax (exp2 domain): 16 scores/lane, tree reductions ----
      float t8[8];
      #pragma unroll
      for (int i = 0; i < 8; i++) t8[i] = fmaxf(sc[i], sc[i + 8]);
      #pragma unroll
      for (int i = 0; i < 4; i++) t8[i] = fmaxf(t8[i], t8[i + 4]);
      float tm = fmaxf(fmaxf(t8[0], t8[1]), fmaxf(t8[2], t8[3]));
      tm = fmaxf(tm, __shfl_xor(tm, 32));
      if (!__all(tm <= mv + 16.f)){
        float mn = fmaxf(mv, tm);
        float scl = __builtin_amdgcn_exp2f(mv - mn);
        lsp *= scl;
        ao[0] *= scl; ao[1] *= scl; ao[2] *= scl;
        mv = mn;
      }
      float ps[8];
      #pragma unroll
      for (int i = 0; i < 8; i++){
        float e0 = __builtin_amdgcn_exp2f(sc[i] - mv);
        float e1 = __builtin_amdgcn_exp2f(sc[i + 8] - mv);
        sc[i] = e0; sc[i + 8] = e1;
        ps[i] = e0 + e1;
      }
      #pragma unroll
      for (int i = 0; i < 4; i++) ps[i] += ps[i + 4];
      lsp += (ps[0] + ps[1]) + (ps[2] + ps[3]);
      // ---- P -> bf16 B-frags in-register ----
      s8v pfa, pfb;
      MK_PF(sc, 0, pfa)
      MK_PF(sc, 8, pfb)
      // ---- PV subtile j (slot16 independent of dt) ----
      int s0 = 4 * j + hi, s1 = 4 * j + 2 + hi;
      int sl0 = ((s0 << 1) | bbit) ^ rhalf;
      int sl1 = ((s1 << 1) | bbit) ^ rhalf;
      __builtin_amdgcn_s_setprio(1);
      #pragma unroll
      for (int dt = 0; dt < 3; dt++){
        const u16* vr = sVc + (dt * 16 + rhalf) * 128;
        s8v vf0 = *(const s8v*)(vr + sl0 * 8);
        s8v vf1 = *(const s8v*)(vr + sl1 * 8);
        ao[dt] = mfma32(vf0, pfa, ao[dt]);
        ao[dt] = mfma32(vf1, pfb, ao[dt]);
      }
      __builtin_amdgcn_s_setprio(0);
    }
    __syncthreads();
  }
  float ls = lsp + __shfl_xor(lsp, 32);
  float inv = 1.f / ls;
  u16* ob = O + (size_t)((((b << 11) + q) << 4) + h) * 72;
  #pragma unroll
  for (int dt = 0; dt < 3; dt++){
    #pragma unroll
    for (int gp = 0; gp < 4; gp++){
      int d = dt * 32 + gp * 8 + hi * 4;
      if (d < 72){
        u32x2 o2;
        o2.x = cvtpk(ao[dt][gp * 4 + 0] * inv, ao[dt][gp * 4 + 1] * inv);
        o2.y = cvtpk(ao[dt][gp * 4 + 2] * inv, ao[dt][gp * 4 + 3] * inv);
        *(u32x2*)(ob + d) = o2;
      }
    }
  }
#undef STAGE
#undef MK_PF
}

// ---------------- launch ----------------
extern "C" void kernel_launch(void* const* d_in, const int* in_sizes, int n_in,
                              void* d_out, int out_size, void* d_ws, size_t ws_size,
                              hipStream_t stream){
  (void)in_sizes; (void)n_in; (void)out_size; (void)ws_size;
  const float* hs   = (const float*)d_in[0];
  const float* cosp = (const float*)d_in[1];
  const float* sinp = (const float*)d_in[2];
  const float* Wq   = (const float*)d_in[5];
  const float* Wk   = (const float*)d_in[6];
  const float* Wv   = (const float*)d_in[7];
  const float* Wo   = (const float*)d_in[8];
  const float* qnw  = (const float*)d_in[9];
  const float* knw  = (const float*)d_in[10];
  char* ws = (char*)d_ws;
  u16* Xb    = (u16*)(ws);                    // 18,874,368 B (reused as O after gemm1)
  u16* WtQKV = (u16*)(ws + 18874368);         //  5,308,416 B
  u16* Wot   = (u16*)(ws + 24182784);         //  2,654,208 B
  u16* Y     = (u16*)(ws + 26836992);         // 37,748,736 B
  u16* Qp    = (u16*)(ws + 64585728);         // 25,165,824 B (stride 96)
  u16* Kp    = (u16*)(ws + 89751552);         // 16,777,216 B (stride 128)
  u16* Vt    = (u16*)(ws + 106528768);        //  9,437,184 B  (total 115,965,952)
  u16* O     = Xb;

  k_prepx<<<2304, 256, 0, stream>>>(hs, Xb, 8192 * 1152);
  k_transpose4<<<dim3(1296, 4), 256, 0, stream>>>(Wq, Wk, Wv, Wo, WtQKV, Wot);
  k_gemm<0><<<dim3(18, 64), 256, 0, stream>>>(Xb, WtQKV, Y, 8192, 2304, 1152);
  k_normrope<<<8192, 192, 0, stream>>>(Y, cosp, sinp, qnw, knw, Qp, Kp);
  k_vtrans<<<dim3(64, 32), 256, 0, stream>>>(Y, Vt);
  k_attn<<<dim3(32, 16), 512, 0, stream>>>(Qp, Kp, Vt, O);
  k_gemm<1><<<dim3(9, 64), 256, 0, stream>>>(O, Wot, (float*)d_out, 8192, 1152, 1152);
}

// Round 22
// 274.966 us; speedup vs baseline: 1.0075x; 1.0075x over previous
//
#include <hip/hip_runtime.h>

typedef unsigned int u32;
typedef unsigned short u16;
typedef __attribute__((ext_vector_type(8))) short s8v;
typedef __attribute__((ext_vector_type(8))) __bf16 b8v;
typedef __attribute__((ext_vector_type(4))) float f4v;
typedef __attribute__((ext_vector_type(16))) float f32x16;
typedef __attribute__((ext_vector_type(4))) u32 u32x4;
typedef __attribute__((ext_vector_type(2))) u32 u32x2;

#define DEV static __device__ __forceinline__

DEV u32 cvtpk(float a, float b){ u32 r; asm("v_cvt_pk_bf16_f32 %0, %1, %2" : "=v"(r) : "v"(a), "v"(b)); return r; }
DEV u16 f2bf(float x){ return (u16)(cvtpk(x, x) & 0xffffu); }
DEV float bf2f(u16 u){ return __builtin_bit_cast(float, ((u32)u) << 16); }

DEV f4v mfma16(s8v a, s8v b, f4v c){
  return __builtin_amdgcn_mfma_f32_16x16x32_bf16(__builtin_bit_cast(b8v, a), __builtin_bit_cast(b8v, b), c, 0, 0, 0);
}
DEV f32x16 mfma32(s8v a, s8v b, f32x16 c){
  return __builtin_amdgcn_mfma_f32_32x32x16_bf16(__builtin_bit_cast(b8v, a), __builtin_bit_cast(b8v, b), c, 0, 0, 0);
}

DEV void gl_lds16(const void* g, void* l){
  __builtin_amdgcn_global_load_lds((const __attribute__((address_space(1))) u32*)g,
                                   (__attribute__((address_space(3))) u32*)l, 16, 0, 0);
}

// ---------------- prep: X fp32 -> bf16 ----------------
__global__ __launch_bounds__(256) void k_prepx(const float* __restrict__ x, u16* __restrict__ xb, int n){
  int i = (blockIdx.x * 256 + threadIdx.x) * 8;
  if (i >= n) return;
  float4 a = *(const float4*)(x + i);
  float4 b = *(const float4*)(x + i + 4);
  u32x4 o;
  o.x = cvtpk(a.x, a.y); o.y = cvtpk(a.z, a.w);
  o.z = cvtpk(b.x, b.y); o.w = cvtpk(b.z, b.w);
  *(u32x4*)(xb + i) = o;
}

// ---------------- prep: batched transpose of Wq/Wk/Wv/Wo fp32 [1152][N] -> bf16 [N][1152] ----------------
__global__ __launch_bounds__(256) void k_transpose4(const float* __restrict__ Wq, const float* __restrict__ Wk,
                                                    const float* __restrict__ Wv, const float* __restrict__ Wo,
                                                    u16* __restrict__ WtQKV, u16* __restrict__ Wot){
  __shared__ float t[32][33];
  int cse = blockIdx.y;
  const float* src; u16* dst; int N;
  if (cse == 0){ src = Wq; dst = WtQKV;               N = 1152; }
  else if (cse == 1){ src = Wk; dst = WtQKV + 1152 * 1152; N = 576; }
  else if (cse == 2){ src = Wv; dst = WtQKV + 1728 * 1152; N = 576; }
  else { src = Wo; dst = Wot;                         N = 1152; }
  int nt = N >> 5;
  if ((int)blockIdx.x >= 36 * nt) return;
  int k0 = (blockIdx.x / nt) << 5, n0 = (blockIdx.x % nt) << 5;
  int col = threadIdx.x & 31, rw = threadIdx.x >> 5;
  #pragma unroll
  for (int i = 0; i < 4; i++){ int r = rw + i * 8; t[r][col] = src[(k0 + r) * N + n0 + col]; }
  __syncthreads();
  #pragma unroll
  for (int i = 0; i < 4; i++){ int r = rw + i * 8; dst[(n0 + r) * 1152 + k0 + col] = f2bf(t[col][r]); }
}

// ---------------- GEMM: C[M,N] = A[M,K] * Bt[N,K]^T, bf16 in, bf16 or f32 out ----------------
template<int OUTF32>
__global__ __launch_bounds__(256) void k_gemm(const u16* __restrict__ A, const u16* __restrict__ Bt,
                                              void* __restrict__ Cv, int M, int N, int K){
  __shared__ u16 sA[128 * 64];
  __shared__ u16 sB[128 * 64];
  int tid = threadIdx.x, w = tid >> 6, lane = tid & 63, g = lane >> 4, c = lane & 15;
  int n0 = blockIdx.x << 7, m0 = blockIdx.y << 7;
  int wr = w >> 1, wc = w & 1;
  f4v acc[4][4] = {};
  int srow = lane >> 3;
  int sslot = (lane & 7) ^ srow;
  const u16* Abase = A + (m0 + srow) * K + sslot * 8;
  const u16* Bbase = Bt + (n0 + srow) * K + sslot * 8;
  #pragma unroll 1
  for (int kt = 0; kt < K; kt += 64){
    #pragma unroll
    for (int ii = 0; ii < 4; ii++){
      int i = w * 4 + ii;
      gl_lds16(Abase + i * 8 * K + kt, sA + i * 512);
      gl_lds16(Bbase + i * 8 * K + kt, sB + i * 512);
    }
    __syncthreads();
    #pragma unroll
    for (int kk = 0; kk < 2; kk++){
      s8v af[4], bfr[4];
      #pragma unroll
      for (int mi = 0; mi < 4; mi++){
        int r = (wr << 6) + (mi << 4) + c;
        int slot = ((kk << 2) + g) ^ (r & 7);
        af[mi] = *(const s8v*)(sA + r * 64 + slot * 8);
      }
      #pragma unroll
      for (int ni = 0; ni < 4; ni++){
        int r = (wc << 6) + (ni << 4) + c;
        int slot = ((kk << 2) + g) ^ (r & 7);
        bfr[ni] = *(const s8v*)(sB + r * 64 + slot * 8);
      }
      #pragma unroll
      for (int mi = 0; mi < 4; mi++)
        #pragma unroll
        for (int ni = 0; ni < 4; ni++)
          acc[mi][ni] = mfma16(af[mi], bfr[ni], acc[mi][ni]);
    }
    __syncthreads();
  }
  #pragma unroll
  for (int mi = 0; mi < 4; mi++){
    #pragma unroll
    for (int ni = 0; ni < 4; ni++){
      #pragma unroll
      for (int r = 0; r < 4; r++){
        int m = m0 + (wr << 6) + (mi << 4) + (g << 2) + r;
        int n = n0 + (wc << 6) + (ni << 4) + c;
        if (OUTF32) ((float*)Cv)[m * N + n] = acc[mi][ni][r];
        else        ((u16*)Cv)[m * N + n] = f2bf(acc[mi][ni][r]);
      }
    }
  }
}

// ---------------- RMSNorm + RoPE; vectorized input staging via LDS ----------------
// Q -> stride 96 (zeros 72..95, xlog2e), K -> stride 128 (zeros 72..127)
__global__ __launch_bounds__(192) void k_normrope(const u16* __restrict__ Y, const float* __restrict__ cosp,
      const float* __restrict__ sinp, const float* __restrict__ qnw, const float* __restrict__ knw,
      u16* __restrict__ Qp, u16* __restrict__ Kp){
  __shared__ float ly[1728];
  int token = blockIdx.x;
  int t = threadIdx.x, head = t >> 3, j = t & 7;
  int base = head * 72 + j * 9;
  if (t < 144){
    const u32* yru = (const u32*)(Y + (size_t)token * 2304) + t * 6;
    u32x2 c0 = *(const u32x2*)(yru);
    u32x2 c1 = *(const u32x2*)(yru + 2);
    u32x2 c2 = *(const u32x2*)(yru + 4);
    float* lp = &ly[t * 12];
    f4v f0, f1, f2;
    f0[0] = bf2f((u16)(c0.x & 0xffff)); f0[1] = bf2f((u16)(c0.x >> 16));
    f0[2] = bf2f((u16)(c0.y & 0xffff)); f0[3] = bf2f((u16)(c0.y >> 16));
    f1[0] = bf2f((u16)(c1.x & 0xffff)); f1[1] = bf2f((u16)(c1.x >> 16));
    f1[2] = bf2f((u16)(c1.y & 0xffff)); f1[3] = bf2f((u16)(c1.y >> 16));
    f2[0] = bf2f((u16)(c2.x & 0xffff)); f2[1] = bf2f((u16)(c2.x >> 16));
    f2[2] = bf2f((u16)(c2.y & 0xffff)); f2[3] = bf2f((u16)(c2.y >> 16));
    *(f4v*)(lp) = f0; *(f4v*)(lp + 4) = f1; *(f4v*)(lp + 8) = f2;
  }
  __syncthreads();
  float x[9]; float ss = 0.f;
  #pragma unroll
  for (int i = 0; i < 9; i++){ x[i] = ly[base + i]; ss += x[i] * x[i]; }
  ss += __shfl_xor(ss, 1); ss += __shfl_xor(ss, 2); ss += __shfl_xor(ss, 4);
  float inv = rsqrtf(ss * (1.f / 72.f) + 1e-6f);
  const float* wn = (head < 16) ? qnw : knw;
  #pragma unroll
  for (int i = 0; i < 9; i++){ int d = j * 9 + i; ly[base + i] = x[i] * inv * (1.f + wn[d]); }
  __syncthreads();
  const float* cs = cosp + token * 72;
  const float* sn = sinp + token * 72;
  float scale = (head < 16) ? 1.4426950408889634f : 1.0f;
  float o[9];
  #pragma unroll
  for (int i = 0; i < 9; i++){
    int d = j * 9 + i;
    int dm = (d >= 36) ? d - 36 : d;
    float rot = (dm < 18) ? -ly[head * 72 + d + 18] : ly[head * 72 + d - 18];
    o[i] = (ly[base + i] * cs[d] + rot * sn[d]) * scale;
  }
  int b = token >> 11, s = token & 2047;
  if (head < 16){
    u16* dst = Qp + (size_t)(((b << 4) + head) * 2048 + s) * 96;
    #pragma unroll
    for (int i = 0; i < 9; i++) dst[j * 9 + i] = f2bf(o[i]);
    #pragma unroll
    for (int p2 = 0; p2 < 3; p2++) dst[72 + j * 3 + p2] = 0;
  } else {
    u16* dst = Kp + (size_t)(((b << 3) + (head - 16)) * 2048 + s) * 128;
    #pragma unroll
    for (int i = 0; i < 9; i++) dst[j * 9 + i] = f2bf(o[i]);
    #pragma unroll
    for (int p2 = 0; p2 < 7; p2++) dst[72 + j * 7 + p2] = 0;
  }
}

// ---------------- V: RMSNorm (no scale) + transpose -> Vt [4][8][72][2048] ----------------
__global__ __launch_bounds__(256) void k_vtrans(const u16* __restrict__ Y, u16* __restrict__ Vt){
  __shared__ float lv[72][33];
  int st = blockIdx.x, bk = blockIdx.y;
  int b = bk >> 3, kvh = bk & 7;
  int t = threadIdx.x, tl = t >> 3, j = t & 7;
  int token = (b << 11) + (st << 5) + tl;
  const u16* yr = Y + token * 2304 + 1728 + kvh * 72 + j * 9;
  float x[9]; float ss = 0.f;
  #pragma unroll
  for (int i = 0; i < 9; i++){ x[i] = bf2f(yr[i]); ss += x[i] * x[i]; }
  ss += __shfl_xor(ss, 1); ss += __shfl_xor(ss, 2); ss += __shfl_xor(ss, 4);
  float inv = rsqrtf(ss * (1.f / 72.f) + 1e-6f);
  #pragma unroll
  for (int i = 0; i < 9; i++) lv[j * 9 + i][tl] = x[i] * inv;
  __syncthreads();
  u16* vb = Vt + bk * 72 * 2048 + (st << 5);
  for (int e = t; e < 72 * 32; e += 256){
    int r = e >> 5, cl = e & 31;
    vb[r * 2048 + cl] = f2bf(lv[r][cl]);
  }
}

// ---------------- Flash attention: 32x32x16, KT=64, head-pairing, 2 blocks/CU, per-subtile pipeline ----------------
// grid (32 bk, 16 qt) = 512 blocks, all resident (2/CU, 4 waves/SIMD).
// 8 waves: w<4 -> head 2kv, w>=4 -> head 2kv+1; 32 q-rows/wave; 2 key-subtiles of 32 per 64-key tile.
// Defer-rescale THR=16 (P <= 2^16; ls <= 1.3e8 -- ample fp32/bf16 margin; R13 proved THR=inf safe).
__global__ __launch_bounds__(512, 4) void k_attn(const u16* __restrict__ Qp, const u16* __restrict__ Kp,
                                                 const u16* __restrict__ Vt, u16* __restrict__ O){
  __shared__ u16 sK[2][64 * 128];   // [buf][key][16 slots of 8]; phys slot = s ^ (key&15)   32KB
  __shared__ u16 sV[2][48 * 128];   // [buf][R=d>>1][slot16 of 8 u16]; slot16 = ((sp<<1)|(d&1)) ^ (R&15)  24KB
  int tid = threadIdx.x, w = tid >> 6, lane = tid & 63, hi = lane >> 5, l31 = lane & 31;
  int bk = blockIdx.x, qt = blockIdx.y;     // 16 qt-blocks of bk land on XCD bk&7
  int b = bk >> 3, kv = bk & 7;
  int h = (kv << 1) + (w >> 2);
  int q = (qt << 7) + ((w & 3) << 5) + l31;
  const u16* qb = Qp + (size_t)((((b << 4) + h) << 11) + q) * 96;
  s8v qf[5];
  #pragma unroll
  for (int ds = 0; ds < 5; ds++) qf[ds] = *(const s8v*)(qb + ds * 16 + hi * 8);
  f32x16 ao[3] = {};
  float mv = -3.0e38f, lsp = 0.f;
  const char* kb = (const char*)Kp + (size_t)bk * 2048 * 256;
  const char* vb = (const char*)Vt + (size_t)bk * 72 * 4096;
  int ko[2], kd[2];
  #pragma unroll
  for (int i = 0; i < 2; i++){
    int n = i * 512 + tid;
    int kr = n >> 4, sp = n & 15;
    ko[i] = kr * 256 + ((sp ^ (kr & 15)) << 4);
    kd[i] = n << 4;
  }
  int vo[2], vd[2];
  #pragma unroll
  for (int i = 0; i < 2; i++){
    int n = (i == 0) ? tid : (512 + lane);
    int R = n >> 4, sl = n & 15, v = sl ^ (R & 15);
    vo[i] = (R * 2 + (v & 1)) * 4096 + ((v >> 1) << 4);
    vd[i] = n << 4;
  }
  int rhalf = l31 >> 1, bbit = l31 & 1;   // PV read geometry: R = dt*16 + rhalf, d = dt*32 + l31

#define STAGE(buf, t1) { \
    const char* kt_ = kb + (size_t)(t1) * 16384; \
    gl_lds16(kt_ + ko[0], (char*)sK[buf] + kd[0]); \
    gl_lds16(kt_ + ko[1], (char*)sK[buf] + kd[1]); \
    const char* vt_ = vb + (size_t)(t1) * 128; \
    gl_lds16(vt_ + vo[0], (char*)sV[buf] + vd[0]); \
    if (w == 0) gl_lds16(vt_ + vo[1], (char*)sV[buf] + vd[1]); }

#define MK_PF(S, mlo, PF) { \
      u32 a0 = cvtpk(S[mlo + 0], S[mlo + 1]); \
      u32 a1 = cvtpk(S[mlo + 2], S[mlo + 3]); \
      u32 b0 = cvtpk(S[mlo + 4], S[mlo + 5]); \
      u32 b1 = cvtpk(S[mlo + 6], S[mlo + 7]); \
      asm("v_permlane32_swap_b32 %0, %1" : "+v"(a0), "+v"(b0)); \
      asm("v_permlane32_swap_b32 %0, %1" : "+v"(a1), "+v"(b1)); \
      u32x4 w4 = {a0, a1, b0, b1}; \
      PF = __builtin_bit_cast(s8v, w4); }

  STAGE(0, 0)
  __syncthreads();

  #pragma unroll 1
  for (int t = 0; t < 32; t++){
    int cur = t & 1, nxt = cur ^ 1;
    if (t < 31){ STAGE(nxt, t + 1) }
    const u16* sKc = sK[cur];
    const u16* sVc = sV[cur];
    #pragma unroll
    for (int j = 0; j < 2; j++){
      // ---- QK^T subtile j: C[key][q], keys j*32..j*32+31 ----
      f32x16 sc = {};
      int r = j * 32 + l31;
      __builtin_amdgcn_s_setprio(1);
      #pragma unroll
      for (int ds = 0; ds < 5; ds++){
        int s = ds * 2 + hi;
        s8v kf = *(const s8v*)(sKc + r * 128 + ((s ^ (r & 15)) << 3));
        sc = mfma32(kf, qf[ds], sc);
      }
      __builtin_amdgcn_s_setprio(0);
      // ---- online softmax (exp2 domain): 16 scores/lane, tree reductions ----
      float t8[8];
      #pragma unroll
      for (int i = 0; i < 8; i++) t8[i] = fmaxf(sc[i], sc[i + 8]);
      #pragma unroll
      for (int i = 0; i < 4; i++) t8[i] = fmaxf(t8[i], t8[i + 4]);
      float tm = fmaxf(fmaxf(t8[0], t8[1]), fmaxf(t8[2], t8[3]));
      tm = fmaxf(tm, __shfl_xor(tm, 32));
      if (!__all(tm <= mv + 16.f)){
        float mn = fmaxf(mv, tm);
        float scl = __builtin_amdgcn_exp2f(mv - mn);
        lsp *= scl;
        ao[0] *= scl; ao[1] *= scl; ao[2] *= scl;
        mv = mn;
      }
      float ps[8];
      #pragma unroll
      for (int i = 0; i < 8; i++){
        float e0 = __builtin_amdgcn_exp2f(sc[i] - mv);
        float e1 = __builtin_amdgcn_exp2f(sc[i + 8] - mv);
        sc[i] = e0; sc[i + 8] = e1;
        ps[i] = e0 + e1;
      }
      #pragma unroll
      for (int i = 0; i < 4; i++) ps[i] += ps[i + 4];
      lsp += (ps[0] + ps[1]) + (ps[2] + ps[3]);
      // ---- P -> bf16 B-frags in-register ----
      s8v pfa, pfb;
      MK_PF(sc, 0, pfa)
      MK_PF(sc, 8, pfb)
      // ---- PV subtile j (slot16 independent of dt) ----
      int s0 = 4 * j + hi, s1 = 4 * j + 2 + hi;
      int sl0 = ((s0 << 1) | bbit) ^ rhalf;
      int sl1 = ((s1 << 1) | bbit) ^ rhalf;
      __builtin_amdgcn_s_setprio(1);
      #pragma unroll
      for (int dt = 0; dt < 3; dt++){
        const u16* vr = sVc + (dt * 16 + rhalf) * 128;
        s8v vf0 = *(const s8v*)(vr + sl0 * 8);
        s8v vf1 = *(const s8v*)(vr + sl1 * 8);
        ao[dt] = mfma32(vf0, pfa, ao[dt]);
        ao[dt] = mfma32(vf1, pfb, ao[dt]);
      }
      __builtin_amdgcn_s_setprio(0);
    }
    __syncthreads();
  }
  float ls = lsp + __shfl_xor(lsp, 32);
  float inv = 1.f / ls;
  u16* ob = O + (size_t)((((b << 11) + q) << 4) + h) * 72;
  #pragma unroll
  for (int dt = 0; dt < 3; dt++){
    #pragma unroll
    for (int gp = 0; gp < 4; gp++){
      int d = dt * 32 + gp * 8 + hi * 4;
      if (d < 72){
        u32x2 o2;
        o2.x = cvtpk(ao[dt][gp * 4 + 0] * inv, ao[dt][gp * 4 + 1] * inv);
        o2.y = cvtpk(ao[dt][gp * 4 + 2] * inv, ao[dt][gp * 4 + 3] * inv);
        *(u32x2*)(ob + d) = o2;
      }
    }
  }
#undef STAGE
#undef MK_PF
}

// ---------------- launch ----------------
extern "C" void kernel_launch(void* const* d_in, const int* in_sizes, int n_in,
                              void* d_out, int out_size, void* d_ws, size_t ws_size,
                              hipStream_t stream){
  (void)in_sizes; (void)n_in; (void)out_size; (void)ws_size;
  const float* hs   = (const float*)d_in[0];
  const float* cosp = (const float*)d_in[1];
  const float* sinp = (const float*)d_in[2];
  const float* Wq   = (const float*)d_in[5];
  const float* Wk   = (const float*)d_in[6];
  const float* Wv   = (const float*)d_in[7];
  const float* Wo   = (const float*)d_in[8];
  const float* qnw  = (const float*)d_in[9];
  const float* knw  = (const float*)d_in[10];
  char* ws = (char*)d_ws;
  u16* Xb    = (u16*)(ws);                    // 18,874,368 B (reused as O after gemm1)
  u16* WtQKV = (u16*)(ws + 18874368);         //  5,308,416 B
  u16* Wot   = (u16*)(ws + 24182784);         //  2,654,208 B
  u16* Y     = (u16*)(ws + 26836992);         // 37,748,736 B
  u16* Qp    = (u16*)(ws + 64585728);         // 25,165,824 B (stride 96)
  u16* Kp    = (u16*)(ws + 89751552);         // 16,777,216 B (stride 128)
  u16* Vt    = (u16*)(ws + 106528768);        //  9,437,184 B  (total 115,965,952)
  u16* O     = Xb;

  k_prepx<<<4608, 256, 0, stream>>>(hs, Xb, 8192 * 1152);
  k_transpose4<<<dim3(1296, 4), 256, 0, stream>>>(Wq, Wk, Wv, Wo, WtQKV, Wot);
  k_gemm<0><<<dim3(18, 64), 256, 0, stream>>>(Xb, WtQKV, Y, 8192, 2304, 1152);
  k_normrope<<<8192, 192, 0, stream>>>(Y, cosp, sinp, qnw, knw, Qp, Kp);
  k_vtrans<<<dim3(64, 32), 256, 0, stream>>>(Y, Vt);
  k_attn<<<dim3(32, 16), 512, 0, stream>>>(Qp, Kp, Vt, O);
  k_gemm<1><<<dim3(9, 64), 256, 0, stream>>>(O, Wot, (float*)d_out, 8192, 1152, 1152);
}